// Round 2
// baseline (382.541 us; speedup 1.0000x reference)
//
#include <hip/hip_runtime.h>
#include <hip/hip_bf16.h>
#include <math.h>

// ---------------------------------------------------------------------------
// DIM=256 HEADS=16 DHEAD=16 H=12 W=26 (HW=312)  Hk=3 Wk=6 (J=18)  B=256
// q_map[b,c,s] = q[b,(c*56+s)&255]
// Round 9: resubmit of round-8 occupancy push (bench infra failed; no
// counters). r7 rocprof: Occupancy 23% (1 block x 8 waves/CU; LDS 133KB
// forces 1 block/CU), VALUBusy 32%, MfmaUtil 5.4%, HBM 2.4% ->
// latency-bound at 2 waves/SIMD. Keep LDS footprint, go 1024 thr/block
// (16 waves = 4 waves/SIMD):
//  - every phase redistributed to 16 waves (conv: 4 j-groups; kv-proj:
//    mtb 0..7 x 2 tiles; sim: 1 head/wave; mlp: ~2.25 tiles/wave;
//    pooled: 16 rows/wave)
//  - h2w: 1 region/wave (32 regions would exceed 160KB LDS); tiles run
//    sequentially per wave -- 4-wave/SIMD occupancy hides the lgkm drain
//    the old 2-region interleave was hiding
//  - soft_acc rows split in half across lane pairs (l, l^16): lv[9]+wAcc[9]
//    (VGPR cap is 128 at 4 waves/SIMD; r7 used 120 -> must shed regs);
//    row max/sum combined via one shfl_xor(16); all 16 waves participate
//  - W1/W2/W3 fragment loads moved after setup phases (don't overlap
//    wreg[36] conv pressure)
// ---------------------------------------------------------------------------

typedef __attribute__((ext_vector_type(8))) short short8;   // 8 bf16
typedef __attribute__((ext_vector_type(4))) float floatx4;

union U16 { uint4 u; short8 s; };

#define MFMA(A, B, C) __builtin_amdgcn_mfma_f32_16x16x32_bf16((A), (B), (C), 0, 0, 0)

__device__ __forceinline__ unsigned int f2bf(float f) {   // RNE f32->bf16 (low 16)
    unsigned int u = __float_as_uint(f);
    u += 0x7fffu + ((u >> 16) & 1u);
    return u >> 16;
}
__device__ __forceinline__ unsigned int pk2(float a, float b) {   // HW cvt_pk
    __hip_bfloat162 h = __float22bfloat162_rn(make_float2(a, b));
    union { __hip_bfloat162 h; unsigned int u; } cv; cv.h = h;
    return cv.u;
}
__device__ __forceinline__ float bf2f(unsigned short v) {
    return __uint_as_float((unsigned int)v << 16);
}
__device__ __forceinline__ uint4 pack8(float4 a, float4 b) {
    uint4 r;
    r.x = pk2(a.x, a.y); r.y = pk2(a.z, a.w);
    r.z = pk2(b.x, b.y); r.w = pk2(b.z, b.w);
    return r;
}

// ===========================================================================
__global__ __launch_bounds__(1024, 1) void k_all(
    const float* __restrict__ x, const float* __restrict__ q,
    const float* __restrict__ w_dw, const float* __restrict__ b_dw,
    const float* __restrict__ w_pw,
    const float* __restrict__ wk, const float* __restrict__ wv,
    const float* __restrict__ w_out, const float* __restrict__ b_out,
    const float* __restrict__ cw1, const float* __restrict__ cb1,
    const float* __restrict__ cw2, const float* __restrict__ cb2,
    const float* __restrict__ cw3, const float* __restrict__ cb3,
    const float* __restrict__ conv_w, const float* __restrict__ conv_b,
    const float* __restrict__ ln_g, const float* __restrict__ ln_b,
    float* __restrict__ out)
{
    const int b = blockIdx.x, tid = threadIdx.x;
    const int w = tid >> 6, lane = tid & 63;       // w in 0..15
    const int n = lane & 15, qd = lane >> 4;

    // ---- persistent LDS (~19.9 KB) ----
    __shared__ float qf_s[256];
    __shared__ unsigned short q_sb[256];            // bf16(q*0.25)
    __shared__ unsigned short v_sb[5120];           // v bf16 [256][20]
    __shared__ float F0[468], F1[216];              // log tables [26][18], [12][18]
    __shared__ unsigned int lutxy[312];             // ix | iy<<16
    __shared__ float off_s[36], n0_s[18], n1_s[18];
    __shared__ float sx0[18], sy0[18], swx[18], swy[18];
    __shared__ float b2_s[64], b3_s[16];
    __shared__ float wA_s[288];
    __shared__ __align__(16) float m_s[256];
    __shared__ float pooled_s[256], redb[24];
    // ---- union region (113152 B) ----
    //   [0 .. 78336)  : S_ double buffer, 2 x [32 il][18 j][17 h] f32 (39168 B)
    //   [78336 .. end): h2w per-wave regions [16 wave][16 rows x 34 uints]
    __shared__ __align__(16) unsigned char UB[113152];
    float* Sbuf = (float*)UB;
    unsigned short* kvT = (unsigned short*)UB;       // [18 j][264 c] bf16 9504B
    float* qsw = (float*)UB;                         // 16 copies x 258 = 16512B
    float* t_s = (float*)(UB + 16512);               // [18 p][256 c] 18432B
    unsigned short* k_sb = (unsigned short*)(UB + 16512);  // k bf16 [256][20]
    unsigned int* h2w = (unsigned int*)(UB + 78336); // [16 wave][544 uints]
    float* wred = (float*)UB;                        // [1024 slot][9 jl] 36864B

    // ---- stage 0 ----
    if (tid < 256) {
        const float qv = q[b * 256 + tid];
        qf_s[tid] = qv;
        q_sb[tid] = (unsigned short)f2bf(qv * 0.25f);
    }
    for (int u = tid; u < 4128; u += 1024) {
        const int r = u / 258, i = u - r * 258;
        qsw[u] = (i < 256) ? q[b * 256 + i] : 0.f;
    }
    if (tid < 312) {
        const int iy = tid / 26;
        lutxy[tid] = (unsigned int)(tid - iy * 26) | ((unsigned int)iy << 16);
    }
    if (tid < 64) b2_s[tid] = cb2[tid];
    if (tid < 16) b3_s[tid] = cb3[tid];
    __syncthreads();

    // ---- depthwise conv 6x6 s4 p1 + GELU -> t_s (4-5 outputs/thread) ----
    {
        const int c = tid & 255, g = tid >> 8;     // g: 0..3
        float wreg[36];
        const float4* wdw4 = (const float4*)w_dw;  // [c][36] contiguous
        #pragma unroll
        for (int i = 0; i < 9; ++i) {
            const float4 t4 = wdw4[c * 9 + i];
            wreg[i * 4 + 0] = t4.x; wreg[i * 4 + 1] = t4.y;
            wreg[i * 4 + 2] = t4.z; wreg[i * 4 + 3] = t4.w;
        }
        const float bv = b_dw[c];
        const int cb = (c * 56) & 255;
        const int cp = (c & 15) * 258;
        #pragma unroll
        for (int it = 0; it < 5; ++it) {
            const int p = g + it * 4;
            if (p < 18) {
                const int jh = (p >= 12) ? 2 : ((p >= 6) ? 1 : 0);
                const int jw = p - jh * 6;
                float acc = bv;
                #pragma unroll
                for (int kh = 0; kh < 6; ++kh) {
                    const int ih = jh * 4 - 1 + kh;
                    if (ih < 0 || ih >= 12) continue;
                    const int rb = ih * 26;
                    #pragma unroll
                    for (int kw = 0; kw < 6; ++kw) {
                        const int iw = jw * 4 - 1 + kw;
                        if (iw < 0 || iw >= 26) continue;
                        acc += wreg[kh * 6 + kw] * qsw[cp + ((cb + rb + iw) & 255)];
                    }
                }
                t_s[p * 256 + c] = 0.5f * acc * (1.0f + erff(acc * 0.70710678118654752f));
            }
        }
    }
    __syncthreads();

    // ---- offsets: 36 dots over 256 channels (16 waves) ----
    for (int oi = w; oi < 36; oi += 16) {
        const int o = oi / 18, p = oi - o * 18;
        float s = 0.f;
        for (int c = lane; c < 256; c += 64) s += w_pw[o * 256 + c] * t_s[p * 256 + c];
        for (int d = 32; d > 0; d >>= 1) s += __shfl_down(s, d, 64);
        if (lane == 0) off_s[oi] = 4.0f * tanhf(s);
    }
    __syncthreads();

    // ---- grid coords + bilinear params ----
    if (tid < 18) {
        const int j = tid, jh = j / 6, jw = j - jh * 6;
        const float vg0 = (float)jw + off_s[j];
        const float vg1 = (float)jh + off_s[18 + j];
        const float n0 = 2.0f * vg0 / 2.0f - 1.0f;
        const float n1 = 2.0f * vg1 / 5.0f - 1.0f;
        n0_s[j] = n0; n1_s[j] = n1;
        const float xp = ((n0 + 1.0f) * 26.0f - 1.0f) * 0.5f;
        const float yp = ((n1 + 1.0f) * 12.0f - 1.0f) * 0.5f;
        const float x0 = floorf(xp), y0 = floorf(yp);
        sx0[j] = x0; sy0[j] = y0; swx[j] = xp - x0; swy[j] = yp - y0;
    }
    __syncthreads();

    // ---- bilinear sample -> kvT bf16 [j][264]; F0/F1 log tables ----
    {
        const int c = tid & 255, g = tid >> 8;     // 4-5 samples/thread
        const float* xb = x + ((size_t)b * 256 + c) * 312;
        #pragma unroll
        for (int jj = 0; jj < 5; ++jj) {
            const int j = g + jj * 4;
            if (j < 18) {
                const int x0 = (int)sx0[j], y0 = (int)sy0[j];
                const int x1 = x0 + 1, y1 = y0 + 1;
                const float wx1 = swx[j], wy1 = swy[j];
                const float wx0 = 1.f - wx1, wy0 = 1.f - wy1;
                const bool xv0 = (x0 >= 0) & (x0 < 26), xv1 = (x1 >= 0) & (x1 < 26);
                const bool yv0 = (y0 >= 0) & (y0 < 12), yv1 = (y1 >= 0) & (y1 < 12);
                const float v00 = (xv0 & yv0) ? xb[y0 * 26 + x0] : 0.f;
                const float v01 = (xv1 & yv0) ? xb[y0 * 26 + x1] : 0.f;
                const float v10 = (xv0 & yv1) ? xb[y1 * 26 + x0] : 0.f;
                const float v11 = (xv1 & yv1) ? xb[y1 * 26 + x1] : 0.f;
                const float val = wy0 * (wx0 * v00 + wx1 * v01) + wy1 * (wx0 * v10 + wx1 * v11);
                kvT[j * 264 + c] = (unsigned short)f2bf(val);
            }
        }
    }
    for (int u = tid; u < 684; u += 1024) {
        if (u < 468) {
            const int ixv = u / 18, j = u - ixv * 18;
            const float p0 = (float)ixv * (2.0f / 11.0f) - 1.0f - n0_s[j];
            F0[u] = copysignf(__logf(1.0f + fabsf(p0)), p0);
        } else {
            const int u2 = u - 468;
            const int iyv = u2 / 18, j = u2 - iyv * 18;
            const float p1 = (float)iyv * (2.0f / 25.0f) - 1.0f - n1_s[j];
            F1[u2] = copysignf(__logf(1.0f + fabsf(p1)), p1);
        }
    }
    __syncthreads();

    // ---- k/v projection via MFMA: wave w -> matrix (w&1), mtb = w>>1 ----
    {
        const int m2 = w & 1, mtb = w >> 1;        // mtb 0..7
        const float4* wm4 = (const float4*)(m2 ? wv : wk);
        floatx4 pa[2][2];
        #pragma unroll
        for (int a = 0; a < 2; ++a) {
            pa[a][0] = (floatx4){0.f, 0.f, 0.f, 0.f};
            pa[a][1] = (floatx4){0.f, 0.f, 0.f, 0.f};
        }
        #pragma unroll 2
        for (int ks = 0; ks < 8; ++ks) {
            U16 b0, b1;
            b0.u = *(const uint4*)(kvT + n * 264 + ks * 32 + qd * 8);
            b1.u = make_uint4(0u, 0u, 0u, 0u);
            if (n < 2) b1.u = *(const uint4*)(kvT + (16 + n) * 264 + ks * 32 + qd * 8);
            #pragma unroll
            for (int mtl = 0; mtl < 2; ++mtl) {
                const int mt = mtb + mtl * 8;
                const int f4i = (mt * 16 + n) * 64 + ks * 8 + qd * 2;
                U16 A; A.u = pack8(wm4[f4i], wm4[f4i + 1]);
                pa[mtl][0] = MFMA(A.s, b0.s, pa[mtl][0]);
                pa[mtl][1] = MFMA(A.s, b1.s, pa[mtl][1]);
            }
        }
        unsigned short* dst = m2 ? v_sb : k_sb;
        #pragma unroll
        for (int mtl = 0; mtl < 2; ++mtl) {
            const int mt = mtb + mtl * 8;
            #pragma unroll
            for (int r = 0; r < 4; ++r) {
                const int o = mt * 16 + qd * 4 + r;
                dst[o * 20 + n] = (unsigned short)f2bf(pa[mtl][0][r]);
                if (n < 2) dst[o * 20 + 16 + n] = (unsigned short)f2bf(pa[mtl][1][r]);
            }
        }
    }
    __syncthreads();

    // ---- per-lane weight fragments (late load: bounds setup-phase VGPRs) ----
    uint4 W2f[4][2], W3f[2];
    {
        const float4* cw2_4 = (const float4*)cw2;
        #pragma unroll
        for (int mtl = 0; mtl < 4; ++mtl)
            #pragma unroll
            for (int ks = 0; ks < 2; ++ks) {
                const int base = (mtl * 16 + n) * 16 + ks * 8 + qd * 2;
                W2f[mtl][ks] = pack8(cw2_4[base], cw2_4[base + 1]);
            }
        const float4* cw3_4 = (const float4*)cw3;
        #pragma unroll
        for (int ks = 0; ks < 2; ++ks) {
            const int base = n * 16 + ks * 8 + qd * 2;
            W3f[ks] = pack8(cw3_4[base], cw3_4[base + 1]);
        }
    }
    float W1a[16], W1b[16], B1r[16];
    #pragma unroll
    for (int kk = 0; kk < 16; ++kk) {
        const int kid = (kk < 8) ? (qd * 8 + kk) : (32 + qd * 8 + kk - 8);
        W1a[kk] = cw1[kid * 2]; W1b[kk] = cw1[kid * 2 + 1]; B1r[kk] = cb1[kid];
    }

    // ---- Bk fragments for sim (wave w -> head w) ----
    uint4 BkU[2];
    #pragma unroll
    for (int jt = 0; jt < 2; ++jt) {
        unsigned int u0 = 0, u1 = 0, u2 = 0, u3 = 0;
        if (qd < 2 && (jt == 0 || n < 2)) {
            const int j = jt * 16 + n;
            const int cb0 = (w * 16 + qd * 8) * 20 + j;
            u0 = (unsigned)k_sb[cb0] | ((unsigned)k_sb[cb0 + 20] << 16);
            u1 = (unsigned)k_sb[cb0 + 40] | ((unsigned)k_sb[cb0 + 60] << 16);
            u2 = (unsigned)k_sb[cb0 + 80] | ((unsigned)k_sb[cb0 + 100] << 16);
            u3 = (unsigned)k_sb[cb0 + 120] | ((unsigned)k_sb[cb0 + 140] << 16);
        }
        BkU[jt] = make_uint4(u0, u1, u2, u3);
    }
    __syncthreads();   // k_sb dead; S_/h2w regions live from here

    // ---- pipelined chunk loop: 10 chunks of 32 i's (last 24) ----
    float wAcc[9];
    #pragma unroll
    for (int jl = 0; jl < 9; ++jl) wAcc[jl] = 0.f;

    // softmax + conv-weighted accumulation, rows half-split across (l, l^16)
    auto soft_acc = [&](int chp, const float* Sp) {
        const int h = tid & 15, hf = (tid >> 4) & 1, il = tid >> 5;
        const int CIp = (chp == 9) ? 24 : 32;
        if (il < CIp) {                                   // wave-uniform
            const float cwv = conv_w[chp * 32 + il];
            float lv[9];
            const float* row = Sp + (il * 18 + hf * 9) * 17 + h;
            #pragma unroll
            for (int jl = 0; jl < 9; ++jl) lv[jl] = row[jl * 17];
            float m = lv[0];
            #pragma unroll
            for (int jl = 1; jl < 9; ++jl) m = fmaxf(m, lv[jl]);
            m = fmaxf(m, __shfl_xor(m, 16, 64));
            float s = 0.f;
            #pragma unroll
            for (int jl = 0; jl < 9; ++jl) { lv[jl] = __expf(lv[jl] - m); s += lv[jl]; }
            s += __shfl_xor(s, 16, 64);
            const float wgt = cwv / s;
            #pragma unroll
            for (int jl = 0; jl < 9; ++jl) wAcc[jl] = fmaf(wgt, lv[jl], wAcc[jl]);
        }
    };

    for (int ch = 0; ch < 10; ++ch) {
        float* Sc = Sbuf + (ch & 1) * 9792;
        const float* Sp = Sbuf + ((ch & 1) ^ 1) * 9792;
        const int ibase = ch * 32;

        // (a) sim: wave w -> head w; 2 i-groups x 2 j-tiles -> Sc
        {
            const int base = w * 16 + qd * 8;
            #pragma unroll
            for (int ig = 0; ig < 2; ++ig) {
                unsigned int a0 = 0, a1 = 0, a2 = 0, a3u = 0;
                if (qd < 2) {
                    const int ii = ibase + ig * 16 + n;
                    a0 = (unsigned)q_sb[((base + 0) * 56 + ii) & 255] |
                         ((unsigned)q_sb[((base + 1) * 56 + ii) & 255] << 16);
                    a1 = (unsigned)q_sb[((base + 2) * 56 + ii) & 255] |
                         ((unsigned)q_sb[((base + 3) * 56 + ii) & 255] << 16);
                    a2 = (unsigned)q_sb[((base + 4) * 56 + ii) & 255] |
                         ((unsigned)q_sb[((base + 5) * 56 + ii) & 255] << 16);
                    a3u = (unsigned)q_sb[((base + 6) * 56 + ii) & 255] |
                          ((unsigned)q_sb[((base + 7) * 56 + ii) & 255] << 16);
                }
                U16 Af; Af.u = make_uint4(a0, a1, a2, a3u);
                #pragma unroll
                for (int jt = 0; jt < 2; ++jt) {
                    U16 Bf; Bf.u = BkU[jt];
                    floatx4 D = {0.f, 0.f, 0.f, 0.f};
                    D = MFMA(Af.s, Bf.s, D);
                    const int j = jt * 16 + n;
                    if (j < 18) {
                        #pragma unroll
                        for (int r = 0; r < 4; ++r)
                            Sc[((ig * 16 + qd * 4 + r) * 18 + j) * 17 + w] = D[r];
                    }
                }
            }
        }
        // (c of ch-1) overlapped with (a): different buffer
        if (ch > 0) soft_acc(ch - 1, Sp);
        __syncthreads();

        // (b) CPB MLP + logits; 36 tiles over 16 waves, 1 h2w region/wave
        {
            auto mlp1 = [&](int t) {
                const int ig = (t >= 18) ? 1 : 0;
                const int j = t - ig * 18;
                const int i0 = ibase + ig * 16 + n;
                const unsigned int lv2 = lutxy[(i0 < 312) ? i0 : 311];
                const int ix = (int)(lv2 & 0xffffu), iy = (int)(lv2 >> 16);
                const float f0 = F0[ix * 18 + j];
                const float f1 = F1[iy * 18 + j];
                U16 ub0, ub1;
                {
                    unsigned int uu[8];
                    #pragma unroll
                    for (int kp = 0; kp < 8; ++kp) {
                        const float ha = fmaxf(fmaf(W1a[2*kp],   f0, fmaf(W1b[2*kp],   f1, B1r[2*kp])),   0.f);
                        const float hb = fmaxf(fmaf(W1a[2*kp+1], f0, fmaf(W1b[2*kp+1], f1, B1r[2*kp+1])), 0.f);
                        uu[kp] = pk2(ha, hb);
                    }
                    ub0.u = make_uint4(uu[0], uu[1], uu[2], uu[3]);
                    ub1.u = make_uint4(uu[4], uu[5], uu[6], uu[7]);
                }
                // GEMM2 -> h2 to this wave's LDS region
                unsigned int* hw = h2w + w * 544 + n * 34;
                #pragma unroll
                for (int mtl = 0; mtl < 4; ++mtl) {
                    U16 A0, A1; A0.u = W2f[mtl][0]; A1.u = W2f[mtl][1];
                    floatx4 acc = {0.f, 0.f, 0.f, 0.f};
                    acc = MFMA(A0.s, ub0.s, acc);
                    acc = MFMA(A1.s, ub1.s, acc);
                    const float e0 = fmaxf(acc[0] + b2_s[mtl*16 + qd*4 + 0], 0.f);
                    const float e1 = fmaxf(acc[1] + b2_s[mtl*16 + qd*4 + 1], 0.f);
                    const float e2 = fmaxf(acc[2] + b2_s[mtl*16 + qd*4 + 2], 0.f);
                    const float e3 = fmaxf(acc[3] + b2_s[mtl*16 + qd*4 + 3], 0.f);
                    hw[mtl * 8 + qd * 2]     = pk2(e0, e1);
                    hw[mtl * 8 + qd * 2 + 1] = pk2(e2, e3);
                }
                // GEMM3 (compiler inserts the wave-local lgkm drain)
                const unsigned int* hwr = h2w + w * 544;
                U16 uc0, uc1;
                uc0.u = *(const uint4*)(hwr + n * 34 + qd * 4);
                uc1.u = *(const uint4*)(hwr + n * 34 + 16 + qd * 4);
                U16 A0, A1; A0.u = W3f[0]; A1.u = W3f[1];
                floatx4 a3 = {0.f, 0.f, 0.f, 0.f};
                a3 = MFMA(A0.s, uc0.s, a3);
                a3 = MFMA(A1.s, uc1.s, a3);
                float* sp = Sc + ((ig * 16 + n) * 18 + j) * 17 + qd * 4;
                #pragma unroll
                for (int r = 0; r < 4; ++r) sp[r] = a3[r] + b3_s[qd * 4 + r] + sp[r];
            };
            mlp1(w);
            mlp1(w + 16);
            if (w < 4) mlp1(32 + w);
        }
        __syncthreads();
    }
    // drain: softmax for final chunk (buffer 9&1 = 1)
    soft_acc(9, Sbuf + 9792);

    // ---- reduce wAcc over 32 il-slots -> wA_s[h][j]; conv_w sum ----
    // wred aliases S buffer 0 (36864B < 39168B); soft_acc(9) read buffer 1.
    #pragma unroll
    for (int jl = 0; jl < 9; ++jl) wred[tid * 9 + jl] = wAcc[jl];
    {
        float v = 0.f;
        for (int u = tid; u < 312; u += 1024) v += conv_w[u];
        for (int d = 32; d > 0; d >>= 1) v += __shfl_down(v, d, 64);
        if (lane == 0) redb[w] = v;
    }
    __syncthreads();
    if (tid < 288) {
        const int h = tid / 18, j2 = tid - h * 18;
        const int hf = (j2 >= 9) ? 1 : 0, jl = j2 - hf * 9;
        float s = 0.f;
        #pragma unroll
        for (int sl = 0; sl < 32; ++sl) s += wred[(sl * 32 + hf * 16 + h) * 9 + jl];
        wA_s[tid] = s;
    }
    __syncthreads();

    // ---- m[c] = sum_j wA[h][j] * v[c][j] ----
    if (tid < 256) {
        const int hb = (tid >> 4) * 18;
        float acc = 0.f;
        #pragma unroll
        for (int j = 0; j < 18; ++j) acc += wA_s[hb + j] * bf2f(v_sb[tid * 20 + j]);
        m_s[tid] = acc;
    }
    __syncthreads();

    float Ssum = 0.f;
    #pragma unroll
    for (int i = 0; i < 16; ++i) Ssum += redb[i];

    // ---- pooled = w_out . m  (16 waves x 16 rows, coalesced float4) ----
    {
        const float4 mm = *(const float4*)(m_s + lane * 4);
        for (int ol = 0; ol < 16; ++ol) {
            const int o = w * 16 + ol;
            const float4 wq = *(const float4*)(w_out + o * 256 + lane * 4);
            float d = wq.x * mm.x + wq.y * mm.y + wq.z * mm.z + wq.w * mm.w;
            for (int dd = 32; dd > 0; dd >>= 1) d += __shfl_down(d, dd, 64);
            if (lane == 0) pooled_s[o] = d;
        }
    }
    __syncthreads();

    // ---- residual + LayerNorm (first 4 waves) ----
    if (tid < 256) {
        const float y = pooled_s[tid] + b_out[tid] * Ssum + conv_b[0] + qf_s[tid];
        float s1 = y, s2 = y * y;
        for (int d = 32; d > 0; d >>= 1) { s1 += __shfl_down(s1, d, 64); s2 += __shfl_down(s2, d, 64); }
        if (lane == 0) { redb[16 + w] = s1; redb[20 + w] = s2; }
    }
    __syncthreads();
    if (tid < 256) {
        const float y = pooled_s[tid] + b_out[tid] * Ssum + conv_b[0] + qf_s[tid];
        const float S1 = redb[16] + redb[17] + redb[18] + redb[19];
        const float S2 = redb[20] + redb[21] + redb[22] + redb[23];
        const float mu = S1 * (1.0f / 256.0f);
        const float var = S2 * (1.0f / 256.0f) - mu * mu;
        out[b * 256 + tid] = (y - mu) * rsqrtf(var + 1e-5f) * ln_g[tid] + ln_b[tid];
    }
}

// ===========================================================================
extern "C" void kernel_launch(void* const* d_in, const int* in_sizes, int n_in,
                              void* d_out, int out_size, void* d_ws, size_t ws_size,
                              hipStream_t stream) {
    const float* x       = (const float*)d_in[0];
    const float* q       = (const float*)d_in[1];
    const float* w_dw    = (const float*)d_in[2];
    const float* b_dwp   = (const float*)d_in[3];
    const float* w_pw    = (const float*)d_in[4];
    const float* wk      = (const float*)d_in[5];
    const float* wv      = (const float*)d_in[6];
    const float* w_out   = (const float*)d_in[7];
    const float* b_out   = (const float*)d_in[8];
    const float* cw1     = (const float*)d_in[9];
    const float* cb1     = (const float*)d_in[10];
    const float* cw2     = (const float*)d_in[11];
    const float* cb2     = (const float*)d_in[12];
    const float* cw3     = (const float*)d_in[13];
    const float* cb3     = (const float*)d_in[14];
    const float* conv_w  = (const float*)d_in[15];
    const float* conv_b  = (const float*)d_in[16];
    const float* ln_g    = (const float*)d_in[17];
    const float* ln_b    = (const float*)d_in[18];
    float* out = (float*)d_out;

    k_all<<<256, 1024, 0, stream>>>(x, q, w_dw, b_dwp, w_pw, wk, wv, w_out, b_out,
                                    cw1, cb1, cw2, cb2, cw3, cb3,
                                    conv_w, conv_b, ln_g, ln_b, out);
}

// Round 3
// 364.019 us; speedup vs baseline: 1.0509x; 1.0509x over previous
//
#include <hip/hip_runtime.h>
#include <hip/hip_bf16.h>
#include <math.h>

// ---------------------------------------------------------------------------
// DIM=256 HEADS=16 DHEAD=16 H=12 W=26 (HW=312)  Hk=3 Wk=6 (J=18)  B=256
// q_map[b,c,s] = q[b,(c*56+s)&255]
// Round 10: fix r9's scratch-spill regression. r9 rocprof: Occupancy 45%
// (prediction hit) but VGPR_Count=64 (compiler heuristic) ->
// WRITE_SIZE 256KB->164MB, FETCH 27->267MB = spill traffic; dur 143->264us.
// Fixes:
//  - amdgpu_waves_per_eu(4,4): LDS (134KB) already caps at 1 block = 4
//    waves/EU, so pin it -> per-wave budget 512/4 = 128 VGPRs, no
//    shrink-to-64 heuristic.
//  - CPB layer-1 weights (W1a/W1b/B1r, 48 VGPRs) -> packed LDS table
//    w1p[4 qd][8 kp][8] (1KB). Broadcast reads (same addr per qd-group),
//    b128+b64 per kp. Persistent regs ~70, peak ~100 < 128.
// Everything else identical to r9 (which verified: absmax 0.015625).
// ---------------------------------------------------------------------------

typedef __attribute__((ext_vector_type(8))) short short8;   // 8 bf16
typedef __attribute__((ext_vector_type(4))) float floatx4;

union U16 { uint4 u; short8 s; };

#define MFMA(A, B, C) __builtin_amdgcn_mfma_f32_16x16x32_bf16((A), (B), (C), 0, 0, 0)

__device__ __forceinline__ unsigned int f2bf(float f) {   // RNE f32->bf16 (low 16)
    unsigned int u = __float_as_uint(f);
    u += 0x7fffu + ((u >> 16) & 1u);
    return u >> 16;
}
__device__ __forceinline__ unsigned int pk2(float a, float b) {   // HW cvt_pk
    __hip_bfloat162 h = __float22bfloat162_rn(make_float2(a, b));
    union { __hip_bfloat162 h; unsigned int u; } cv; cv.h = h;
    return cv.u;
}
__device__ __forceinline__ float bf2f(unsigned short v) {
    return __uint_as_float((unsigned int)v << 16);
}
__device__ __forceinline__ uint4 pack8(float4 a, float4 b) {
    uint4 r;
    r.x = pk2(a.x, a.y); r.y = pk2(a.z, a.w);
    r.z = pk2(b.x, b.y); r.w = pk2(b.z, b.w);
    return r;
}

// ===========================================================================
__global__ __attribute__((amdgpu_flat_work_group_size(1024, 1024)))
__attribute__((amdgpu_waves_per_eu(4, 4))) void k_all(
    const float* __restrict__ x, const float* __restrict__ q,
    const float* __restrict__ w_dw, const float* __restrict__ b_dw,
    const float* __restrict__ w_pw,
    const float* __restrict__ wk, const float* __restrict__ wv,
    const float* __restrict__ w_out, const float* __restrict__ b_out,
    const float* __restrict__ cw1, const float* __restrict__ cb1,
    const float* __restrict__ cw2, const float* __restrict__ cb2,
    const float* __restrict__ cw3, const float* __restrict__ cb3,
    const float* __restrict__ conv_w, const float* __restrict__ conv_b,
    const float* __restrict__ ln_g, const float* __restrict__ ln_b,
    float* __restrict__ out)
{
    const int b = blockIdx.x, tid = threadIdx.x;
    const int w = tid >> 6, lane = tid & 63;       // w in 0..15
    const int n = lane & 15, qd = lane >> 4;

    // ---- persistent LDS (~21 KB) ----
    __shared__ float qf_s[256];
    __shared__ unsigned short q_sb[256];            // bf16(q*0.25)
    __shared__ unsigned short v_sb[5120];           // v bf16 [256][20]
    __shared__ float F0[468], F1[216];              // log tables [26][18], [12][18]
    __shared__ unsigned int lutxy[312];             // ix | iy<<16
    __shared__ float off_s[36], n0_s[18], n1_s[18];
    __shared__ float sx0[18], sy0[18], swx[18], swy[18];
    __shared__ float b2_s[64], b3_s[16];
    __shared__ __align__(16) float w1p[4][8][8];    // [qd][kp][6 used]
    __shared__ float wA_s[288];
    __shared__ __align__(16) float m_s[256];
    __shared__ float pooled_s[256], redb[24];
    // ---- union region (113152 B) ----
    //   [0 .. 78336)  : S_ double buffer, 2 x [32 il][18 j][17 h] f32 (39168 B)
    //   [78336 .. end): h2w per-wave regions [16 wave][16 rows x 34 uints]
    __shared__ __align__(16) unsigned char UB[113152];
    float* Sbuf = (float*)UB;
    unsigned short* kvT = (unsigned short*)UB;       // [18 j][264 c] bf16 9504B
    float* qsw = (float*)UB;                         // 16 copies x 258 = 16512B
    float* t_s = (float*)(UB + 16512);               // [18 p][256 c] 18432B
    unsigned short* k_sb = (unsigned short*)(UB + 16512);  // k bf16 [256][20]
    unsigned int* h2w = (unsigned int*)(UB + 78336); // [16 wave][544 uints]
    float* wred = (float*)UB;                        // [1024 slot][9 jl] 36864B

    // ---- stage 0 ----
    if (tid < 256) {
        const float qv = q[b * 256 + tid];
        qf_s[tid] = qv;
        q_sb[tid] = (unsigned short)f2bf(qv * 0.25f);
    }
    for (int u = tid; u < 4128; u += 1024) {
        const int r = u / 258, i = u - r * 258;
        qsw[u] = (i < 256) ? q[b * 256 + i] : 0.f;
    }
    if (tid < 312) {
        const int iy = tid / 26;
        lutxy[tid] = (unsigned int)(tid - iy * 26) | ((unsigned int)iy << 16);
    }
    if (tid < 64) b2_s[tid] = cb2[tid];
    if (tid < 16) b3_s[tid] = cb3[tid];
    if (tid < 32) {                                  // CPB layer-1 weight table
        const int qdi = tid >> 3, kp = tid & 7;
        const int kk0 = 2 * kp, kk1 = 2 * kp + 1;
        const int kid0 = (kk0 < 8) ? (qdi * 8 + kk0) : (32 + qdi * 8 + kk0 - 8);
        const int kid1 = (kk1 < 8) ? (qdi * 8 + kk1) : (32 + qdi * 8 + kk1 - 8);
        w1p[qdi][kp][0] = cw1[kid0 * 2];
        w1p[qdi][kp][1] = cw1[kid0 * 2 + 1];
        w1p[qdi][kp][2] = cb1[kid0];
        w1p[qdi][kp][3] = cw1[kid1 * 2];
        w1p[qdi][kp][4] = cw1[kid1 * 2 + 1];
        w1p[qdi][kp][5] = cb1[kid1];
    }
    __syncthreads();

    // ---- depthwise conv 6x6 s4 p1 + GELU -> t_s (4-5 outputs/thread) ----
    {
        const int c = tid & 255, g = tid >> 8;     // g: 0..3
        float wreg[36];
        const float4* wdw4 = (const float4*)w_dw;  // [c][36] contiguous
        #pragma unroll
        for (int i = 0; i < 9; ++i) {
            const float4 t4 = wdw4[c * 9 + i];
            wreg[i * 4 + 0] = t4.x; wreg[i * 4 + 1] = t4.y;
            wreg[i * 4 + 2] = t4.z; wreg[i * 4 + 3] = t4.w;
        }
        const float bv = b_dw[c];
        const int cb = (c * 56) & 255;
        const int cp = (c & 15) * 258;
        #pragma unroll
        for (int it = 0; it < 5; ++it) {
            const int p = g + it * 4;
            if (p < 18) {
                const int jh = (p >= 12) ? 2 : ((p >= 6) ? 1 : 0);
                const int jw = p - jh * 6;
                float acc = bv;
                #pragma unroll
                for (int kh = 0; kh < 6; ++kh) {
                    const int ih = jh * 4 - 1 + kh;
                    if (ih < 0 || ih >= 12) continue;
                    const int rb = ih * 26;
                    #pragma unroll
                    for (int kw = 0; kw < 6; ++kw) {
                        const int iw = jw * 4 - 1 + kw;
                        if (iw < 0 || iw >= 26) continue;
                        acc += wreg[kh * 6 + kw] * qsw[cp + ((cb + rb + iw) & 255)];
                    }
                }
                t_s[p * 256 + c] = 0.5f * acc * (1.0f + erff(acc * 0.70710678118654752f));
            }
        }
    }
    __syncthreads();

    // ---- offsets: 36 dots over 256 channels (16 waves) ----
    for (int oi = w; oi < 36; oi += 16) {
        const int o = oi / 18, p = oi - o * 18;
        float s = 0.f;
        for (int c = lane; c < 256; c += 64) s += w_pw[o * 256 + c] * t_s[p * 256 + c];
        for (int d = 32; d > 0; d >>= 1) s += __shfl_down(s, d, 64);
        if (lane == 0) off_s[oi] = 4.0f * tanhf(s);
    }
    __syncthreads();

    // ---- grid coords + bilinear params ----
    if (tid < 18) {
        const int j = tid, jh = j / 6, jw = j - jh * 6;
        const float vg0 = (float)jw + off_s[j];
        const float vg1 = (float)jh + off_s[18 + j];
        const float n0 = 2.0f * vg0 / 2.0f - 1.0f;
        const float n1 = 2.0f * vg1 / 5.0f - 1.0f;
        n0_s[j] = n0; n1_s[j] = n1;
        const float xp = ((n0 + 1.0f) * 26.0f - 1.0f) * 0.5f;
        const float yp = ((n1 + 1.0f) * 12.0f - 1.0f) * 0.5f;
        const float x0 = floorf(xp), y0 = floorf(yp);
        sx0[j] = x0; sy0[j] = y0; swx[j] = xp - x0; swy[j] = yp - y0;
    }
    __syncthreads();

    // ---- bilinear sample -> kvT bf16 [j][264]; F0/F1 log tables ----
    {
        const int c = tid & 255, g = tid >> 8;     // 4-5 samples/thread
        const float* xb = x + ((size_t)b * 256 + c) * 312;
        #pragma unroll
        for (int jj = 0; jj < 5; ++jj) {
            const int j = g + jj * 4;
            if (j < 18) {
                const int x0 = (int)sx0[j], y0 = (int)sy0[j];
                const int x1 = x0 + 1, y1 = y0 + 1;
                const float wx1 = swx[j], wy1 = swy[j];
                const float wx0 = 1.f - wx1, wy0 = 1.f - wy1;
                const bool xv0 = (x0 >= 0) & (x0 < 26), xv1 = (x1 >= 0) & (x1 < 26);
                const bool yv0 = (y0 >= 0) & (y0 < 12), yv1 = (y1 >= 0) & (y1 < 12);
                const float v00 = (xv0 & yv0) ? xb[y0 * 26 + x0] : 0.f;
                const float v01 = (xv1 & yv0) ? xb[y0 * 26 + x1] : 0.f;
                const float v10 = (xv0 & yv1) ? xb[y1 * 26 + x0] : 0.f;
                const float v11 = (xv1 & yv1) ? xb[y1 * 26 + x1] : 0.f;
                const float val = wy0 * (wx0 * v00 + wx1 * v01) + wy1 * (wx0 * v10 + wx1 * v11);
                kvT[j * 264 + c] = (unsigned short)f2bf(val);
            }
        }
    }
    for (int u = tid; u < 684; u += 1024) {
        if (u < 468) {
            const int ixv = u / 18, j = u - ixv * 18;
            const float p0 = (float)ixv * (2.0f / 11.0f) - 1.0f - n0_s[j];
            F0[u] = copysignf(__logf(1.0f + fabsf(p0)), p0);
        } else {
            const int u2 = u - 468;
            const int iyv = u2 / 18, j = u2 - iyv * 18;
            const float p1 = (float)iyv * (2.0f / 25.0f) - 1.0f - n1_s[j];
            F1[u2] = copysignf(__logf(1.0f + fabsf(p1)), p1);
        }
    }
    __syncthreads();

    // ---- k/v projection via MFMA: wave w -> matrix (w&1), mtb = w>>1 ----
    {
        const int m2 = w & 1, mtb = w >> 1;        // mtb 0..7
        const float4* wm4 = (const float4*)(m2 ? wv : wk);
        floatx4 pa[2][2];
        #pragma unroll
        for (int a = 0; a < 2; ++a) {
            pa[a][0] = (floatx4){0.f, 0.f, 0.f, 0.f};
            pa[a][1] = (floatx4){0.f, 0.f, 0.f, 0.f};
        }
        #pragma unroll 2
        for (int ks = 0; ks < 8; ++ks) {
            U16 b0, b1;
            b0.u = *(const uint4*)(kvT + n * 264 + ks * 32 + qd * 8);
            b1.u = make_uint4(0u, 0u, 0u, 0u);
            if (n < 2) b1.u = *(const uint4*)(kvT + (16 + n) * 264 + ks * 32 + qd * 8);
            #pragma unroll
            for (int mtl = 0; mtl < 2; ++mtl) {
                const int mt = mtb + mtl * 8;
                const int f4i = (mt * 16 + n) * 64 + ks * 8 + qd * 2;
                U16 A; A.u = pack8(wm4[f4i], wm4[f4i + 1]);
                pa[mtl][0] = MFMA(A.s, b0.s, pa[mtl][0]);
                pa[mtl][1] = MFMA(A.s, b1.s, pa[mtl][1]);
            }
        }
        unsigned short* dst = m2 ? v_sb : k_sb;
        #pragma unroll
        for (int mtl = 0; mtl < 2; ++mtl) {
            const int mt = mtb + mtl * 8;
            #pragma unroll
            for (int r = 0; r < 4; ++r) {
                const int o = mt * 16 + qd * 4 + r;
                dst[o * 20 + n] = (unsigned short)f2bf(pa[mtl][0][r]);
                if (n < 2) dst[o * 20 + 16 + n] = (unsigned short)f2bf(pa[mtl][1][r]);
            }
        }
    }
    __syncthreads();

    // ---- per-lane weight fragments (late load: bounds setup-phase VGPRs) ----
    uint4 W2f[4][2], W3f[2];
    {
        const float4* cw2_4 = (const float4*)cw2;
        #pragma unroll
        for (int mtl = 0; mtl < 4; ++mtl)
            #pragma unroll
            for (int ks = 0; ks < 2; ++ks) {
                const int base = (mtl * 16 + n) * 16 + ks * 8 + qd * 2;
                W2f[mtl][ks] = pack8(cw2_4[base], cw2_4[base + 1]);
            }
        const float4* cw3_4 = (const float4*)cw3;
        #pragma unroll
        for (int ks = 0; ks < 2; ++ks) {
            const int base = n * 16 + ks * 8 + qd * 2;
            W3f[ks] = pack8(cw3_4[base], cw3_4[base + 1]);
        }
    }

    // ---- Bk fragments for sim (wave w -> head w) ----
    uint4 BkU[2];
    #pragma unroll
    for (int jt = 0; jt < 2; ++jt) {
        unsigned int u0 = 0, u1 = 0, u2 = 0, u3 = 0;
        if (qd < 2 && (jt == 0 || n < 2)) {
            const int j = jt * 16 + n;
            const int cb0 = (w * 16 + qd * 8) * 20 + j;
            u0 = (unsigned)k_sb[cb0] | ((unsigned)k_sb[cb0 + 20] << 16);
            u1 = (unsigned)k_sb[cb0 + 40] | ((unsigned)k_sb[cb0 + 60] << 16);
            u2 = (unsigned)k_sb[cb0 + 80] | ((unsigned)k_sb[cb0 + 100] << 16);
            u3 = (unsigned)k_sb[cb0 + 120] | ((unsigned)k_sb[cb0 + 140] << 16);
        }
        BkU[jt] = make_uint4(u0, u1, u2, u3);
    }
    __syncthreads();   // k_sb dead; S_/h2w regions live from here

    // ---- pipelined chunk loop: 10 chunks of 32 i's (last 24) ----
    float wAcc[9];
    #pragma unroll
    for (int jl = 0; jl < 9; ++jl) wAcc[jl] = 0.f;

    // softmax + conv-weighted accumulation, rows half-split across (l, l^16)
    auto soft_acc = [&](int chp, const float* Sp) {
        const int h = tid & 15, hf = (tid >> 4) & 1, il = tid >> 5;
        const int CIp = (chp == 9) ? 24 : 32;
        if (il < CIp) {                                   // wave-uniform
            const float cwv = conv_w[chp * 32 + il];
            float lv[9];
            const float* row = Sp + (il * 18 + hf * 9) * 17 + h;
            #pragma unroll
            for (int jl = 0; jl < 9; ++jl) lv[jl] = row[jl * 17];
            float m = lv[0];
            #pragma unroll
            for (int jl = 1; jl < 9; ++jl) m = fmaxf(m, lv[jl]);
            m = fmaxf(m, __shfl_xor(m, 16, 64));
            float s = 0.f;
            #pragma unroll
            for (int jl = 0; jl < 9; ++jl) { lv[jl] = __expf(lv[jl] - m); s += lv[jl]; }
            s += __shfl_xor(s, 16, 64);
            const float wgt = cwv / s;
            #pragma unroll
            for (int jl = 0; jl < 9; ++jl) wAcc[jl] = fmaf(wgt, lv[jl], wAcc[jl]);
        }
    };

    for (int ch = 0; ch < 10; ++ch) {
        float* Sc = Sbuf + (ch & 1) * 9792;
        const float* Sp = Sbuf + ((ch & 1) ^ 1) * 9792;
        const int ibase = ch * 32;

        // (a) sim: wave w -> head w; 2 i-groups x 2 j-tiles -> Sc
        {
            const int base = w * 16 + qd * 8;
            #pragma unroll
            for (int ig = 0; ig < 2; ++ig) {
                unsigned int a0 = 0, a1 = 0, a2 = 0, a3u = 0;
                if (qd < 2) {
                    const int ii = ibase + ig * 16 + n;
                    a0 = (unsigned)q_sb[((base + 0) * 56 + ii) & 255] |
                         ((unsigned)q_sb[((base + 1) * 56 + ii) & 255] << 16);
                    a1 = (unsigned)q_sb[((base + 2) * 56 + ii) & 255] |
                         ((unsigned)q_sb[((base + 3) * 56 + ii) & 255] << 16);
                    a2 = (unsigned)q_sb[((base + 4) * 56 + ii) & 255] |
                         ((unsigned)q_sb[((base + 5) * 56 + ii) & 255] << 16);
                    a3u = (unsigned)q_sb[((base + 6) * 56 + ii) & 255] |
                          ((unsigned)q_sb[((base + 7) * 56 + ii) & 255] << 16);
                }
                U16 Af; Af.u = make_uint4(a0, a1, a2, a3u);
                #pragma unroll
                for (int jt = 0; jt < 2; ++jt) {
                    U16 Bf; Bf.u = BkU[jt];
                    floatx4 D = {0.f, 0.f, 0.f, 0.f};
                    D = MFMA(Af.s, Bf.s, D);
                    const int j = jt * 16 + n;
                    if (j < 18) {
                        #pragma unroll
                        for (int r = 0; r < 4; ++r)
                            Sc[((ig * 16 + qd * 4 + r) * 18 + j) * 17 + w] = D[r];
                    }
                }
            }
        }
        // (c of ch-1) overlapped with (a): different buffer
        if (ch > 0) soft_acc(ch - 1, Sp);
        __syncthreads();

        // (b) CPB MLP + logits; 36 tiles over 16 waves, 1 h2w region/wave
        {
            auto mlp1 = [&](int t) {
                const int ig = (t >= 18) ? 1 : 0;
                const int j = t - ig * 18;
                const int i0 = ibase + ig * 16 + n;
                const unsigned int lv2 = lutxy[(i0 < 312) ? i0 : 311];
                const int ix = (int)(lv2 & 0xffffu), iy = (int)(lv2 >> 16);
                const float f0 = F0[ix * 18 + j];
                const float f1 = F1[iy * 18 + j];
                U16 ub0, ub1;
                {
                    unsigned int uu[8];
                    #pragma unroll
                    for (int kp = 0; kp < 8; ++kp) {
                        const float* wp = &w1p[qd][kp][0];
                        const float ha = fmaxf(fmaf(wp[0], f0, fmaf(wp[1], f1, wp[2])), 0.f);
                        const float hb = fmaxf(fmaf(wp[3], f0, fmaf(wp[4], f1, wp[5])), 0.f);
                        uu[kp] = pk2(ha, hb);
                    }
                    ub0.u = make_uint4(uu[0], uu[1], uu[2], uu[3]);
                    ub1.u = make_uint4(uu[4], uu[5], uu[6], uu[7]);
                }
                // GEMM2 -> h2 to this wave's LDS region
                unsigned int* hw = h2w + w * 544 + n * 34;
                #pragma unroll
                for (int mtl = 0; mtl < 4; ++mtl) {
                    U16 A0, A1; A0.u = W2f[mtl][0]; A1.u = W2f[mtl][1];
                    floatx4 acc = {0.f, 0.f, 0.f, 0.f};
                    acc = MFMA(A0.s, ub0.s, acc);
                    acc = MFMA(A1.s, ub1.s, acc);
                    const float e0 = fmaxf(acc[0] + b2_s[mtl*16 + qd*4 + 0], 0.f);
                    const float e1 = fmaxf(acc[1] + b2_s[mtl*16 + qd*4 + 1], 0.f);
                    const float e2 = fmaxf(acc[2] + b2_s[mtl*16 + qd*4 + 2], 0.f);
                    const float e3 = fmaxf(acc[3] + b2_s[mtl*16 + qd*4 + 3], 0.f);
                    hw[mtl * 8 + qd * 2]     = pk2(e0, e1);
                    hw[mtl * 8 + qd * 2 + 1] = pk2(e2, e3);
                }
                // GEMM3 (compiler inserts the wave-local lgkm drain)
                const unsigned int* hwr = h2w + w * 544;
                U16 uc0, uc1;
                uc0.u = *(const uint4*)(hwr + n * 34 + qd * 4);
                uc1.u = *(const uint4*)(hwr + n * 34 + 16 + qd * 4);
                U16 A0, A1; A0.u = W3f[0]; A1.u = W3f[1];
                floatx4 a3 = {0.f, 0.f, 0.f, 0.f};
                a3 = MFMA(A0.s, uc0.s, a3);
                a3 = MFMA(A1.s, uc1.s, a3);
                float* sp = Sc + ((ig * 16 + n) * 18 + j) * 17 + qd * 4;
                #pragma unroll
                for (int r = 0; r < 4; ++r) sp[r] = a3[r] + b3_s[qd * 4 + r] + sp[r];
            };
            mlp1(w);
            mlp1(w + 16);
            if (w < 4) mlp1(32 + w);
        }
        __syncthreads();
    }
    // drain: softmax for final chunk (buffer 9&1 = 1)
    soft_acc(9, Sbuf + 9792);

    // ---- reduce wAcc over 32 il-slots -> wA_s[h][j]; conv_w sum ----
    // wred aliases S buffer 0 (36864B < 39168B); soft_acc(9) read buffer 1.
    #pragma unroll
    for (int jl = 0; jl < 9; ++jl) wred[tid * 9 + jl] = wAcc[jl];
    {
        float v = 0.f;
        for (int u = tid; u < 312; u += 1024) v += conv_w[u];
        for (int d = 32; d > 0; d >>= 1) v += __shfl_down(v, d, 64);
        if (lane == 0) redb[w] = v;
    }
    __syncthreads();
    if (tid < 288) {
        const int h = tid / 18, j2 = tid - h * 18;
        const int hf = (j2 >= 9) ? 1 : 0, jl = j2 - hf * 9;
        float s = 0.f;
        #pragma unroll
        for (int sl = 0; sl < 32; ++sl) s += wred[(sl * 32 + hf * 16 + h) * 9 + jl];
        wA_s[tid] = s;
    }
    __syncthreads();

    // ---- m[c] = sum_j wA[h][j] * v[c][j] ----
    if (tid < 256) {
        const int hb = (tid >> 4) * 18;
        float acc = 0.f;
        #pragma unroll
        for (int j = 0; j < 18; ++j) acc += wA_s[hb + j] * bf2f(v_sb[tid * 20 + j]);
        m_s[tid] = acc;
    }
    __syncthreads();

    float Ssum = 0.f;
    #pragma unroll
    for (int i = 0; i < 16; ++i) Ssum += redb[i];

    // ---- pooled = w_out . m  (16 waves x 16 rows, coalesced float4) ----
    {
        const float4 mm = *(const float4*)(m_s + lane * 4);
        for (int ol = 0; ol < 16; ++ol) {
            const int o = w * 16 + ol;
            const float4 wq = *(const float4*)(w_out + o * 256 + lane * 4);
            float d = wq.x * mm.x + wq.y * mm.y + wq.z * mm.z + wq.w * mm.w;
            for (int dd = 32; dd > 0; dd >>= 1) d += __shfl_down(d, dd, 64);
            if (lane == 0) pooled_s[o] = d;
        }
    }
    __syncthreads();

    // ---- residual + LayerNorm (first 4 waves) ----
    if (tid < 256) {
        const float y = pooled_s[tid] + b_out[tid] * Ssum + conv_b[0] + qf_s[tid];
        float s1 = y, s2 = y * y;
        for (int d = 32; d > 0; d >>= 1) { s1 += __shfl_down(s1, d, 64); s2 += __shfl_down(s2, d, 64); }
        if (lane == 0) { redb[16 + w] = s1; redb[20 + w] = s2; }
    }
    __syncthreads();
    if (tid < 256) {
        const float y = pooled_s[tid] + b_out[tid] * Ssum + conv_b[0] + qf_s[tid];
        const float S1 = redb[16] + redb[17] + redb[18] + redb[19];
        const float S2 = redb[20] + redb[21] + redb[22] + redb[23];
        const float mu = S1 * (1.0f / 256.0f);
        const float var = S2 * (1.0f / 256.0f) - mu * mu;
        out[b * 256 + tid] = (y - mu) * rsqrtf(var + 1e-5f) * ln_g[tid] + ln_b[tid];
    }
}

// ===========================================================================
extern "C" void kernel_launch(void* const* d_in, const int* in_sizes, int n_in,
                              void* d_out, int out_size, void* d_ws, size_t ws_size,
                              hipStream_t stream) {
    const float* x       = (const float*)d_in[0];
    const float* q       = (const float*)d_in[1];
    const float* w_dw    = (const float*)d_in[2];
    const float* b_dwp   = (const float*)d_in[3];
    const float* w_pw    = (const float*)d_in[4];
    const float* wk      = (const float*)d_in[5];
    const float* wv      = (const float*)d_in[6];
    const float* w_out   = (const float*)d_in[7];
    const float* b_out   = (const float*)d_in[8];
    const float* cw1     = (const float*)d_in[9];
    const float* cb1     = (const float*)d_in[10];
    const float* cw2     = (const float*)d_in[11];
    const float* cb2     = (const float*)d_in[12];
    const float* cw3     = (const float*)d_in[13];
    const float* cb3     = (const float*)d_in[14];
    const float* conv_w  = (const float*)d_in[15];
    const float* conv_b  = (const float*)d_in[16];
    const float* ln_g    = (const float*)d_in[17];
    const float* ln_b    = (const float*)d_in[18];
    float* out = (float*)d_out;

    k_all<<<256, 1024, 0, stream>>>(x, q, w_dw, b_dwp, w_pw, wk, wv, w_out, b_out,
                                    cw1, cb1, cw2, cb2, cw3, cb3,
                                    conv_w, conv_b, ln_g, ln_b, out);
}

// Round 4
// 307.790 us; speedup vs baseline: 1.2429x; 1.1827x over previous
//
#include <hip/hip_runtime.h>
#include <hip/hip_bf16.h>
#include <math.h>

// ---------------------------------------------------------------------------
// DIM=256 HEADS=16 DHEAD=16 H=12 W=26 (HW=312)  Hk=3 Wk=6 (J=18)  B=256
// q_map[b,c,s] = q[b,(c*56+s)&255]
// Round 11: 768 threads (12 waves = 3 waves/SIMD), __launch_bounds__(768,3).
// r9/r10 post-mortem: 1024-thr shape pins VGPR=64 (8-waves/EU register
// target) regardless of launch_bounds(1024,1) or amdgpu_waves_per_eu(4,4)
// -> 160 dwords/thread spill (WRITE 167MB, FETCH 266MB). 768-thr cap is
// 512/3 -> 168 regs, demand ~90 (w1p table kept in LDS from r10) -> no
// spill, +50% wave parallelism over the proven r7 512-thr base.
// Redistribution for 12 waves:
//  - sim: waves 0..7 -> head w + softmax; waves 8..11 -> heads w, w+4
//    (critical path max(1 head + soft, 2 heads) < r7's 2 heads + soft)
//  - kv-proj: 32 (matrix,row-tile) tasks strided over 12 waves
//  - CPB MLP: 36 tiles = 12 waves x 3 exactly
//  - soft_acc: r7 full-row form (lv[18], no shfl) on tid<512
//  - conv/bilinear: 3 c-groups x 6 outputs; offsets: 3 dots/wave
// ---------------------------------------------------------------------------

typedef __attribute__((ext_vector_type(8))) short short8;   // 8 bf16
typedef __attribute__((ext_vector_type(4))) float floatx4;

union U16 { uint4 u; short8 s; };

#define MFMA(A, B, C) __builtin_amdgcn_mfma_f32_16x16x32_bf16((A), (B), (C), 0, 0, 0)

__device__ __forceinline__ unsigned int f2bf(float f) {   // RNE f32->bf16 (low 16)
    unsigned int u = __float_as_uint(f);
    u += 0x7fffu + ((u >> 16) & 1u);
    return u >> 16;
}
__device__ __forceinline__ unsigned int pk2(float a, float b) {   // HW cvt_pk
    __hip_bfloat162 h = __float22bfloat162_rn(make_float2(a, b));
    union { __hip_bfloat162 h; unsigned int u; } cv; cv.h = h;
    return cv.u;
}
__device__ __forceinline__ float bf2f(unsigned short v) {
    return __uint_as_float((unsigned int)v << 16);
}
__device__ __forceinline__ uint4 pack8(float4 a, float4 b) {
    uint4 r;
    r.x = pk2(a.x, a.y); r.y = pk2(a.z, a.w);
    r.z = pk2(b.x, b.y); r.w = pk2(b.z, b.w);
    return r;
}

// ===========================================================================
__global__ __launch_bounds__(768, 3) void k_all(
    const float* __restrict__ x, const float* __restrict__ q,
    const float* __restrict__ w_dw, const float* __restrict__ b_dw,
    const float* __restrict__ w_pw,
    const float* __restrict__ wk, const float* __restrict__ wv,
    const float* __restrict__ w_out, const float* __restrict__ b_out,
    const float* __restrict__ cw1, const float* __restrict__ cb1,
    const float* __restrict__ cw2, const float* __restrict__ cb2,
    const float* __restrict__ cw3, const float* __restrict__ cb3,
    const float* __restrict__ conv_w, const float* __restrict__ conv_b,
    const float* __restrict__ ln_g, const float* __restrict__ ln_b,
    float* __restrict__ out)
{
    const int b = blockIdx.x, tid = threadIdx.x;
    const int w = tid >> 6, lane = tid & 63;       // w in 0..11
    const int n = lane & 15, qd = lane >> 4;

    // ---- persistent LDS (~21 KB) ----
    __shared__ float qf_s[256];
    __shared__ unsigned short q_sb[256];            // bf16(q*0.25)
    __shared__ unsigned short v_sb[5120];           // v bf16 [256][20]
    __shared__ float F0[468], F1[216];              // log tables [26][18], [12][18]
    __shared__ unsigned int lutxy[312];             // ix | iy<<16
    __shared__ float off_s[36], n0_s[18], n1_s[18];
    __shared__ float sx0[18], sy0[18], swx[18], swy[18];
    __shared__ float b2_s[64], b3_s[16];
    __shared__ __align__(16) float w1p[4][8][8];    // [qd][kp][6 used]
    __shared__ float wA_s[288];
    __shared__ __align__(16) float m_s[256];
    __shared__ float pooled_s[256], redb[24];
    // ---- union region (113152 B) ----
    //   [0 .. 78336)  : S_ double buffer, 2 x [32 il][18 j][17 h] f32 (39168 B)
    //   [78336 .. end): h2w per-wave regions [12 wave][16 rows x 34 uints]
    __shared__ __align__(16) unsigned char UB[113152];
    float* Sbuf = (float*)UB;
    unsigned short* kvT = (unsigned short*)UB;       // [18 j][264 c] bf16 9504B
    float* qsw = (float*)UB;                         // 16 copies x 258 = 16512B
    float* t_s = (float*)(UB + 16512);               // [18 p][256 c] 18432B
    unsigned short* k_sb = (unsigned short*)(UB + 16512);  // k bf16 [256][20]
    unsigned int* h2w = (unsigned int*)(UB + 78336); // [12 wave][544 uints]
    float* wred = (float*)UB;                        // [512 slot][18 j] 36864B

    // ---- stage 0 ----
    if (tid < 256) {
        const float qv = q[b * 256 + tid];
        qf_s[tid] = qv;
        q_sb[tid] = (unsigned short)f2bf(qv * 0.25f);
    }
    for (int u = tid; u < 4128; u += 768) {
        const int r = u / 258, i = u - r * 258;
        qsw[u] = (i < 256) ? q[b * 256 + i] : 0.f;
    }
    if (tid < 312) {
        const int iy = tid / 26;
        lutxy[tid] = (unsigned int)(tid - iy * 26) | ((unsigned int)iy << 16);
    }
    if (tid < 64) b2_s[tid] = cb2[tid];
    if (tid < 16) b3_s[tid] = cb3[tid];
    if (tid < 32) {                                  // CPB layer-1 weight table
        const int qdi = tid >> 3, kp = tid & 7;
        const int kk0 = 2 * kp, kk1 = 2 * kp + 1;
        const int kid0 = (kk0 < 8) ? (qdi * 8 + kk0) : (32 + qdi * 8 + kk0 - 8);
        const int kid1 = (kk1 < 8) ? (qdi * 8 + kk1) : (32 + qdi * 8 + kk1 - 8);
        w1p[qdi][kp][0] = cw1[kid0 * 2];
        w1p[qdi][kp][1] = cw1[kid0 * 2 + 1];
        w1p[qdi][kp][2] = cb1[kid0];
        w1p[qdi][kp][3] = cw1[kid1 * 2];
        w1p[qdi][kp][4] = cw1[kid1 * 2 + 1];
        w1p[qdi][kp][5] = cb1[kid1];
    }
    __syncthreads();

    // ---- depthwise conv 6x6 s4 p1 + GELU -> t_s (6 outputs/thread) ----
    {
        const int c = tid & 255, g = tid >> 8;     // g: 0..2
        float wreg[36];
        const float4* wdw4 = (const float4*)w_dw;  // [c][36] contiguous
        #pragma unroll
        for (int i = 0; i < 9; ++i) {
            const float4 t4 = wdw4[c * 9 + i];
            wreg[i * 4 + 0] = t4.x; wreg[i * 4 + 1] = t4.y;
            wreg[i * 4 + 2] = t4.z; wreg[i * 4 + 3] = t4.w;
        }
        const float bv = b_dw[c];
        const int cb = (c * 56) & 255;
        const int cp = (c & 15) * 258;
        #pragma unroll
        for (int it = 0; it < 6; ++it) {
            const int p = g + it * 3;              // covers 0..17 over g=0..2
            const int jh = (p >= 12) ? 2 : ((p >= 6) ? 1 : 0);
            const int jw = p - jh * 6;
            float acc = bv;
            #pragma unroll
            for (int kh = 0; kh < 6; ++kh) {
                const int ih = jh * 4 - 1 + kh;
                if (ih < 0 || ih >= 12) continue;
                const int rb = ih * 26;
                #pragma unroll
                for (int kw = 0; kw < 6; ++kw) {
                    const int iw = jw * 4 - 1 + kw;
                    if (iw < 0 || iw >= 26) continue;
                    acc += wreg[kh * 6 + kw] * qsw[cp + ((cb + rb + iw) & 255)];
                }
            }
            t_s[p * 256 + c] = 0.5f * acc * (1.0f + erff(acc * 0.70710678118654752f));
        }
    }
    __syncthreads();

    // ---- offsets: 36 dots over 256 channels (12 waves) ----
    for (int oi = w; oi < 36; oi += 12) {
        const int o = oi / 18, p = oi - o * 18;
        float s = 0.f;
        for (int c = lane; c < 256; c += 64) s += w_pw[o * 256 + c] * t_s[p * 256 + c];
        for (int d = 32; d > 0; d >>= 1) s += __shfl_down(s, d, 64);
        if (lane == 0) off_s[oi] = 4.0f * tanhf(s);
    }
    __syncthreads();

    // ---- grid coords + bilinear params ----
    if (tid < 18) {
        const int j = tid, jh = j / 6, jw = j - jh * 6;
        const float vg0 = (float)jw + off_s[j];
        const float vg1 = (float)jh + off_s[18 + j];
        const float n0 = 2.0f * vg0 / 2.0f - 1.0f;
        const float n1 = 2.0f * vg1 / 5.0f - 1.0f;
        n0_s[j] = n0; n1_s[j] = n1;
        const float xp = ((n0 + 1.0f) * 26.0f - 1.0f) * 0.5f;
        const float yp = ((n1 + 1.0f) * 12.0f - 1.0f) * 0.5f;
        const float x0 = floorf(xp), y0 = floorf(yp);
        sx0[j] = x0; sy0[j] = y0; swx[j] = xp - x0; swy[j] = yp - y0;
    }
    __syncthreads();

    // ---- bilinear sample -> kvT bf16 [j][264]; F0/F1 log tables ----
    {
        const int c = tid & 255, g = tid >> 8;     // 6 samples/thread
        const float* xb = x + ((size_t)b * 256 + c) * 312;
        #pragma unroll
        for (int jj = 0; jj < 6; ++jj) {
            const int j = g + jj * 3;
            const int x0 = (int)sx0[j], y0 = (int)sy0[j];
            const int x1 = x0 + 1, y1 = y0 + 1;
            const float wx1 = swx[j], wy1 = swy[j];
            const float wx0 = 1.f - wx1, wy0 = 1.f - wy1;
            const bool xv0 = (x0 >= 0) & (x0 < 26), xv1 = (x1 >= 0) & (x1 < 26);
            const bool yv0 = (y0 >= 0) & (y0 < 12), yv1 = (y1 >= 0) & (y1 < 12);
            const float v00 = (xv0 & yv0) ? xb[y0 * 26 + x0] : 0.f;
            const float v01 = (xv1 & yv0) ? xb[y0 * 26 + x1] : 0.f;
            const float v10 = (xv0 & yv1) ? xb[y1 * 26 + x0] : 0.f;
            const float v11 = (xv1 & yv1) ? xb[y1 * 26 + x1] : 0.f;
            const float val = wy0 * (wx0 * v00 + wx1 * v01) + wy1 * (wx0 * v10 + wx1 * v11);
            kvT[j * 264 + c] = (unsigned short)f2bf(val);
        }
    }
    for (int u = tid; u < 684; u += 768) {
        if (u < 468) {
            const int ixv = u / 18, j = u - ixv * 18;
            const float p0 = (float)ixv * (2.0f / 11.0f) - 1.0f - n0_s[j];
            F0[u] = copysignf(__logf(1.0f + fabsf(p0)), p0);
        } else {
            const int u2 = u - 468;
            const int iyv = u2 / 18, j = u2 - iyv * 18;
            const float p1 = (float)iyv * (2.0f / 25.0f) - 1.0f - n1_s[j];
            F1[u2] = copysignf(__logf(1.0f + fabsf(p1)), p1);
        }
    }
    __syncthreads();

    // ---- k/v projection via MFMA: 32 (matrix,row-tile) tasks / 12 waves ----
    for (int task = w; task < 32; task += 12) {
        const int m2 = task & 1, mt = task >> 1;   // mt 0..15
        const float4* wm4 = (const float4*)(m2 ? wv : wk);
        floatx4 p0 = {0.f, 0.f, 0.f, 0.f}, p1 = {0.f, 0.f, 0.f, 0.f};
        #pragma unroll 2
        for (int ks = 0; ks < 8; ++ks) {
            U16 b0, b1;
            b0.u = *(const uint4*)(kvT + n * 264 + ks * 32 + qd * 8);
            b1.u = make_uint4(0u, 0u, 0u, 0u);
            if (n < 2) b1.u = *(const uint4*)(kvT + (16 + n) * 264 + ks * 32 + qd * 8);
            const int f4i = (mt * 16 + n) * 64 + ks * 8 + qd * 2;
            U16 A; A.u = pack8(wm4[f4i], wm4[f4i + 1]);
            p0 = MFMA(A.s, b0.s, p0);
            p1 = MFMA(A.s, b1.s, p1);
        }
        unsigned short* dst = m2 ? v_sb : k_sb;
        #pragma unroll
        for (int r = 0; r < 4; ++r) {
            const int o = mt * 16 + qd * 4 + r;
            dst[o * 20 + n] = (unsigned short)f2bf(p0[r]);
            if (n < 2) dst[o * 20 + 16 + n] = (unsigned short)f2bf(p1[r]);
        }
    }
    __syncthreads();

    // ---- per-lane weight fragments (late load) ----
    uint4 W2f[4][2], W3f[2];
    {
        const float4* cw2_4 = (const float4*)cw2;
        #pragma unroll
        for (int mtl = 0; mtl < 4; ++mtl)
            #pragma unroll
            for (int ks = 0; ks < 2; ++ks) {
                const int base = (mtl * 16 + n) * 16 + ks * 8 + qd * 2;
                W2f[mtl][ks] = pack8(cw2_4[base], cw2_4[base + 1]);
            }
        const float4* cw3_4 = (const float4*)cw3;
        #pragma unroll
        for (int ks = 0; ks < 2; ++ks) {
            const int base = n * 16 + ks * 8 + qd * 2;
            W3f[ks] = pack8(cw3_4[base], cw3_4[base + 1]);
        }
    }

    // ---- Bk fragments: hh=0 -> head w (all); hh=1 -> head w+4 (w>=8) ----
    uint4 BkU[2][2];
    #pragma unroll
    for (int hh = 0; hh < 2; ++hh)
        #pragma unroll
        for (int jt = 0; jt < 2; ++jt) {
            unsigned int u0 = 0, u1 = 0, u2 = 0, u3 = 0;
            const bool hv = hh ? (w >= 8) : true;
            if (hv && qd < 2 && (jt == 0 || n < 2)) {
                const int h = hh ? (w + 4) : w;    // hh=1: heads 12..15
                const int j = jt * 16 + n;
                const int cb0 = (h * 16 + qd * 8) * 20 + j;
                u0 = (unsigned)k_sb[cb0] | ((unsigned)k_sb[cb0 + 20] << 16);
                u1 = (unsigned)k_sb[cb0 + 40] | ((unsigned)k_sb[cb0 + 60] << 16);
                u2 = (unsigned)k_sb[cb0 + 80] | ((unsigned)k_sb[cb0 + 100] << 16);
                u3 = (unsigned)k_sb[cb0 + 120] | ((unsigned)k_sb[cb0 + 140] << 16);
            }
            BkU[hh][jt] = make_uint4(u0, u1, u2, u3);
        }
    __syncthreads();   // k_sb dead; S_/h2w regions live from here

    // ---- pipelined chunk loop: 10 chunks of 32 i's (last 24) ----
    float wAcc[18];
    #pragma unroll
    for (int j = 0; j < 18; ++j) wAcc[j] = 0.f;

    // softmax + conv-weighted accumulation (threads 0..511, full rows)
    auto soft_acc = [&](int chp, const float* Sp) {
        if (tid < 512) {
            const int il = tid >> 4, h = tid & 15;
            const int CIp = (chp == 9) ? 24 : 32;
            if (il < CIp) {
                const float cwv = conv_w[chp * 32 + il];
                float lv[18];
                const float* row = Sp + (il * 18) * 17 + h;
                #pragma unroll
                for (int j = 0; j < 18; ++j) lv[j] = row[j * 17];
                float m = lv[0];
                #pragma unroll
                for (int j = 1; j < 18; ++j) m = fmaxf(m, lv[j]);
                float s = 0.f;
                #pragma unroll
                for (int j = 0; j < 18; ++j) { lv[j] = __expf(lv[j] - m); s += lv[j]; }
                const float wgt = cwv / s;
                #pragma unroll
                for (int j = 0; j < 18; ++j) wAcc[j] = fmaf(wgt, lv[j], wAcc[j]);
            }
        }
    };

    for (int ch = 0; ch < 10; ++ch) {
        float* Sc = Sbuf + (ch & 1) * 9792;
        const float* Sp = Sbuf + ((ch & 1) ^ 1) * 9792;
        const int ibase = ch * 32;

        // (a) sim: waves 0..7 head w; waves 8..11 heads w, w+4
        #pragma unroll
        for (int hh = 0; hh < 2; ++hh) {
            if (hh == 1 && w < 8) break;           // wave-uniform
            const int h = hh ? (w + 4) : w;
            const int base = h * 16 + qd * 8;
            #pragma unroll
            for (int ig = 0; ig < 2; ++ig) {
                unsigned int a0 = 0, a1 = 0, a2 = 0, a3u = 0;
                if (qd < 2) {
                    const int ii = ibase + ig * 16 + n;
                    a0 = (unsigned)q_sb[((base + 0) * 56 + ii) & 255] |
                         ((unsigned)q_sb[((base + 1) * 56 + ii) & 255] << 16);
                    a1 = (unsigned)q_sb[((base + 2) * 56 + ii) & 255] |
                         ((unsigned)q_sb[((base + 3) * 56 + ii) & 255] << 16);
                    a2 = (unsigned)q_sb[((base + 4) * 56 + ii) & 255] |
                         ((unsigned)q_sb[((base + 5) * 56 + ii) & 255] << 16);
                    a3u = (unsigned)q_sb[((base + 6) * 56 + ii) & 255] |
                          ((unsigned)q_sb[((base + 7) * 56 + ii) & 255] << 16);
                }
                U16 Af; Af.u = make_uint4(a0, a1, a2, a3u);
                #pragma unroll
                for (int jt = 0; jt < 2; ++jt) {
                    U16 Bf; Bf.u = BkU[hh][jt];
                    floatx4 D = {0.f, 0.f, 0.f, 0.f};
                    D = MFMA(Af.s, Bf.s, D);
                    const int j = jt * 16 + n;
                    if (j < 18) {
                        #pragma unroll
                        for (int r = 0; r < 4; ++r)
                            Sc[((ig * 16 + qd * 4 + r) * 18 + j) * 17 + h] = D[r];
                    }
                }
            }
        }
        // (c of ch-1) overlapped with (a): different buffer
        if (ch > 0) soft_acc(ch - 1, Sp);
        __syncthreads();

        // (b) CPB MLP + logits; 36 tiles = 12 waves x 3, 1 h2w region/wave
        {
            auto mlp1 = [&](int t) {
                const int ig = (t >= 18) ? 1 : 0;
                const int j = t - ig * 18;
                const int i0 = ibase + ig * 16 + n;
                const unsigned int lv2 = lutxy[(i0 < 312) ? i0 : 311];
                const int ix = (int)(lv2 & 0xffffu), iy = (int)(lv2 >> 16);
                const float f0 = F0[ix * 18 + j];
                const float f1 = F1[iy * 18 + j];
                U16 ub0, ub1;
                {
                    unsigned int uu[8];
                    #pragma unroll
                    for (int kp = 0; kp < 8; ++kp) {
                        const float* wp = &w1p[qd][kp][0];
                        const float ha = fmaxf(fmaf(wp[0], f0, fmaf(wp[1], f1, wp[2])), 0.f);
                        const float hb = fmaxf(fmaf(wp[3], f0, fmaf(wp[4], f1, wp[5])), 0.f);
                        uu[kp] = pk2(ha, hb);
                    }
                    ub0.u = make_uint4(uu[0], uu[1], uu[2], uu[3]);
                    ub1.u = make_uint4(uu[4], uu[5], uu[6], uu[7]);
                }
                // GEMM2 -> h2 to this wave's LDS region
                unsigned int* hw = h2w + w * 544 + n * 34;
                #pragma unroll
                for (int mtl = 0; mtl < 4; ++mtl) {
                    U16 A0, A1; A0.u = W2f[mtl][0]; A1.u = W2f[mtl][1];
                    floatx4 acc = {0.f, 0.f, 0.f, 0.f};
                    acc = MFMA(A0.s, ub0.s, acc);
                    acc = MFMA(A1.s, ub1.s, acc);
                    const float e0 = fmaxf(acc[0] + b2_s[mtl*16 + qd*4 + 0], 0.f);
                    const float e1 = fmaxf(acc[1] + b2_s[mtl*16 + qd*4 + 1], 0.f);
                    const float e2 = fmaxf(acc[2] + b2_s[mtl*16 + qd*4 + 2], 0.f);
                    const float e3 = fmaxf(acc[3] + b2_s[mtl*16 + qd*4 + 3], 0.f);
                    hw[mtl * 8 + qd * 2]     = pk2(e0, e1);
                    hw[mtl * 8 + qd * 2 + 1] = pk2(e2, e3);
                }
                // GEMM3 (compiler inserts the wave-local lgkm drain)
                const unsigned int* hwr = h2w + w * 544;
                U16 uc0, uc1;
                uc0.u = *(const uint4*)(hwr + n * 34 + qd * 4);
                uc1.u = *(const uint4*)(hwr + n * 34 + 16 + qd * 4);
                U16 A0, A1; A0.u = W3f[0]; A1.u = W3f[1];
                floatx4 a3 = {0.f, 0.f, 0.f, 0.f};
                a3 = MFMA(A0.s, uc0.s, a3);
                a3 = MFMA(A1.s, uc1.s, a3);
                float* sp = Sc + ((ig * 16 + n) * 18 + j) * 17 + qd * 4;
                #pragma unroll
                for (int r = 0; r < 4; ++r) sp[r] = a3[r] + b3_s[qd * 4 + r] + sp[r];
            };
            mlp1(w);
            mlp1(w + 12);
            mlp1(w + 24);
        }
        __syncthreads();
    }
    // drain: softmax for final chunk (buffer 9&1 = 1)
    soft_acc(9, Sbuf + 9792);

    // ---- reduce wAcc over 32 il-slots -> wA_s[h][j]; conv_w sum ----
    // wred aliases S buffer 0 (36864B < 39168B); soft_acc(9) read buffer 1.
    if (tid < 512) {
        #pragma unroll
        for (int j = 0; j < 18; ++j) wred[tid * 18 + j] = wAcc[j];
    }
    {
        float v = 0.f;
        for (int u = tid; u < 312; u += 768) v += conv_w[u];
        for (int d = 32; d > 0; d >>= 1) v += __shfl_down(v, d, 64);
        if (lane == 0) redb[w] = v;
    }
    __syncthreads();
    if (tid < 288) {
        const int h = tid / 18, j = tid - h * 18;
        float s = 0.f;
        #pragma unroll
        for (int sl = 0; sl < 32; ++sl) s += wred[(sl * 16 + h) * 18 + j];
        wA_s[tid] = s;
    }
    __syncthreads();

    // ---- m[c] = sum_j wA[h][j] * v[c][j] ----
    if (tid < 256) {
        const int hb = (tid >> 4) * 18;
        float acc = 0.f;
        #pragma unroll
        for (int j = 0; j < 18; ++j) acc += wA_s[hb + j] * bf2f(v_sb[tid * 20 + j]);
        m_s[tid] = acc;
    }
    __syncthreads();

    float Ssum = 0.f;
    #pragma unroll
    for (int i = 0; i < 12; ++i) Ssum += redb[i];

    // ---- pooled = w_out . m  (12 waves, strided rows, coalesced float4) ----
    {
        const float4 mm = *(const float4*)(m_s + lane * 4);
        for (int o = w; o < 256; o += 12) {
            const float4 wq = *(const float4*)(w_out + o * 256 + lane * 4);
            float d = wq.x * mm.x + wq.y * mm.y + wq.z * mm.z + wq.w * mm.w;
            for (int dd = 32; dd > 0; dd >>= 1) d += __shfl_down(d, dd, 64);
            if (lane == 0) pooled_s[o] = d;
        }
    }
    __syncthreads();

    // ---- residual + LayerNorm (first 4 waves) ----
    if (tid < 256) {
        const float y = pooled_s[tid] + b_out[tid] * Ssum + conv_b[0] + qf_s[tid];
        float s1 = y, s2 = y * y;
        for (int d = 32; d > 0; d >>= 1) { s1 += __shfl_down(s1, d, 64); s2 += __shfl_down(s2, d, 64); }
        if (lane == 0) { redb[16 + w] = s1; redb[20 + w] = s2; }
    }
    __syncthreads();
    if (tid < 256) {
        const float y = pooled_s[tid] + b_out[tid] * Ssum + conv_b[0] + qf_s[tid];
        const float S1 = redb[16] + redb[17] + redb[18] + redb[19];
        const float S2 = redb[20] + redb[21] + redb[22] + redb[23];
        const float mu = S1 * (1.0f / 256.0f);
        const float var = S2 * (1.0f / 256.0f) - mu * mu;
        out[b * 256 + tid] = (y - mu) * rsqrtf(var + 1e-5f) * ln_g[tid] + ln_b[tid];
    }
}

// ===========================================================================
extern "C" void kernel_launch(void* const* d_in, const int* in_sizes, int n_in,
                              void* d_out, int out_size, void* d_ws, size_t ws_size,
                              hipStream_t stream) {
    const float* x       = (const float*)d_in[0];
    const float* q       = (const float*)d_in[1];
    const float* w_dw    = (const float*)d_in[2];
    const float* b_dwp   = (const float*)d_in[3];
    const float* w_pw    = (const float*)d_in[4];
    const float* wk      = (const float*)d_in[5];
    const float* wv      = (const float*)d_in[6];
    const float* w_out   = (const float*)d_in[7];
    const float* b_out   = (const float*)d_in[8];
    const float* cw1     = (const float*)d_in[9];
    const float* cb1     = (const float*)d_in[10];
    const float* cw2     = (const float*)d_in[11];
    const float* cb2     = (const float*)d_in[12];
    const float* cw3     = (const float*)d_in[13];
    const float* cb3     = (const float*)d_in[14];
    const float* conv_w  = (const float*)d_in[15];
    const float* conv_b  = (const float*)d_in[16];
    const float* ln_g    = (const float*)d_in[17];
    const float* ln_b    = (const float*)d_in[18];
    float* out = (float*)d_out;

    k_all<<<256, 768, 0, stream>>>(x, q, w_dw, b_dwp, w_pw, wk, wv, w_out, b_out,
                                   cw1, cb1, cw2, cb2, cw3, cb3,
                                   conv_w, conv_b, ln_g, ln_b, out);
}